// Round 10
// baseline (169.084 us; speedup 1.0000x reference)
//
#include <hip/hip_runtime.h>
#include <cstddef>

// Critic_43104291783486 — round 10: deepen the W pipeline to ~2.8 sub-steps.
//  - W ring: 4x32KB slots; issue W(kt+3) at step kt, drain W(kt+1) at step end.
//  - X: SINGLE 20KB buffer; per step: [barrier A] compute [barrier B: lgkm only]
//    x_write [vmcnt(12) + barrier A'] — raw s_barrier everywhere, so the 12
//    in-flight VMEM ops (X(kt+2), W(kt+2), W(kt+3)) survive every barrier.
//  - W2 halves issued as tiles NK,NK+1 -> slots 0,1; slab in freed slots 2,3.
// Unchanged: grid 256 (weights-once, 1 node/CU), 512 thr / 8 waves, fp16 MFMA
// 16x16x32 (layouts verified r3-r9), W-tile XOR swizzle (r9), phase2.

#define BN 256
#define HD 256
#define FD 64
#define XS 40    // X lds row stride (halves): 80B rows, 16B-aligned
#define SLS 268  // slab row stride (halves)

typedef _Float16 f16x8 __attribute__((ext_vector_type(8)));
typedef _Float16 f16x4 __attribute__((ext_vector_type(4)));
typedef float f32x4 __attribute__((ext_vector_type(4)));

#define GLOAD16(g, l)                                              \
  __builtin_amdgcn_global_load_lds(                                \
      (__attribute__((address_space(1))) void*)(g),                \
      (__attribute__((address_space(3))) void*)(l), 16, 0, 0)

// barrier A: publish LDS writes + drain W(kt+1); keep 12 VMEM in flight
#define WAIT_BAR12()                                                       \
  asm volatile("s_waitcnt vmcnt(12) lgkmcnt(0)" ::: "memory");             \
  __builtin_amdgcn_s_barrier();                                            \
  asm volatile("" ::: "memory");
// barrier B: all waves done READING Xl (lgkmcnt only — vmcnt untouched)
#define BAR_LGKM()                                                         \
  asm volatile("s_waitcnt lgkmcnt(0)" ::: "memory");                       \
  __builtin_amdgcn_s_barrier();                                            \
  asm volatile("" ::: "memory");

// ---------- X staging: 256 rows x 32 k fp32 -> regs -> fp16 LDS ----------
__device__ __forceinline__ void x_load(const float* xs0, const float* xs1, int n,
                                       int kt, int tid, float4 xr[4]) {
  int kOff = kt * 32;
  const float* xs = (kOff < 256) ? xs0 : xs1;   // A-branch: obs then act
  int l = tid & 63, w = tid >> 6;
  const float* base = xs + (size_t)n * HD + (kOff & 255) + (l & 7) * 4;
#pragma unroll
  for (int i = 0; i < 4; ++i) {
    int row = w * 32 + i * 8 + (l >> 3);
    xr[i] = *(const float4*)(base + (size_t)row * (BN * HD));
  }
}
__device__ __forceinline__ void x_write(_Float16* Xl, int tid, const float4 xr[4]) {
  int l = tid & 63, w = tid >> 6;
#pragma unroll
  for (int i = 0; i < 4; ++i) {
    int row = w * 32 + i * 8 + (l >> 3);
    f16x4 v;
    v[0] = (_Float16)xr[i].x; v[1] = (_Float16)xr[i].y;
    v[2] = (_Float16)xr[i].z; v[3] = (_Float16)xr[i].w;
    *(f16x4*)(Xl + row * XS + (l & 7) * 4) = v;
  }
}

// ---------- W1 tile gload: [32][256] fp32, source pre-swizzled (r9) ----------
__device__ __forceinline__ void w1_gload(const float* __restrict__ Wg, float* Wl,
                                         int ktile, int w, int lane) {
#pragma unroll
  for (int s = 0; s < 4; ++s) {
    int rl = w * 4 + s;
    int swz = ((rl >> 3) & 3) << 4;
    const float* src = Wg + (size_t)(ktile * 32 + rl) * HD + ((lane * 4) ^ swz);
    GLOAD16(src, Wl + rl * HD);
  }
}

// ---------- W2 half gload: rows half*128..+127 -> chunk[128][64] (r9) ----------
__device__ __forceinline__ void w2_gload_half(const float* __restrict__ W2g, float* chunk,
                                              int half, int w, int lane) {
#pragma unroll
  for (int s = 0; s < 4; ++s) {
    int rl = (w * 4 + s) * 4;
    int swz = ((rl >> 3) & 3) << 4;
    const float* src = W2g + (size_t)(half * 128 + rl + (lane >> 4)) * FD
                       + (((lane & 15) * 4) ^ swz);
    GLOAD16(src, chunk + rl * FD);
  }
}

// ---------- GEMM1 compute: one 32-k step, 32 MFMA/wave (r9 layouts) ----------
__device__ __forceinline__ void g1_compute(const float* Wc, const _Float16* Xc,
                                           int lrow, int lq, int Nbase, int wm1,
                                           f32x4 acc[8][4]) {
  int lk8 = lq * 8;
  const float* wbase = Wc + lk8 * 256;
  f16x8 b[4];
#pragma unroll
  for (int nf = 0; nf < 4; ++nf) {
    int col = (Nbase + nf * 16 + lrow) ^ (lq << 4);
    f16x8 t;
#pragma unroll
    for (int j = 0; j < 8; ++j) t[j] = (_Float16)wbase[j * 256 + col];
    b[nf] = t;
  }
#pragma unroll
  for (int m = 0; m < 8; ++m) {
    f16x8 a = *(const f16x8*)(Xc + (wm1 * 128 + m * 16 + lrow) * XS + lk8);
#pragma unroll
    for (int nf = 0; nf < 4; ++nf)
      acc[m][nf] = __builtin_amdgcn_mfma_f32_16x16x32_f16(a, b[nf], acc[m][nf], 0, 0, 0);
  }
}

// C(256x256) = X(256xK) @ W1(Kx256), K = NK*32 (NK multiple of 4).
// Ring-4 slots; W2 halves arrive as tiles NK (slot 0) and NK+1 (slot 1).
template <int NK>
__device__ __forceinline__ void run_gemm1(const float* xs0, const float* xs1,
                                          const float* __restrict__ Wg,
                                          const float* __restrict__ W2g,
                                          int n, int tid, int lrow, int lq,
                                          int Nbase, int wm1, int w, int lane,
                                          float* ring, _Float16* Xl,
                                          f32x4 acc[8][4]) {
  float4 xrA[4], xrB[4];
  // prologue: X(0),X(1) and W tiles 0,1,2 in flight
  x_load(xs0, xs1, n, 0, tid, xrA);
  w1_gload(Wg, ring, 0, w, lane);
  x_load(xs0, xs1, n, 1, tid, xrB);
  w1_gload(Wg, ring + 8192, 1, w, lane);
  w1_gload(Wg, ring + 16384, 2, w, lane);
  x_write(Xl, tid, xrA);          // waits X(0) only (oldest); gloads stay
  WAIT_BAR12()                    // drains W(0); keeps X(1),W(1),W(2) = 12
#pragma unroll 1
  for (int kt = 0; kt < NK; ++kt) {
    float* slot = ring + (size_t)(kt & 3) * 8192;
    // issue tile kt+3 (W1, or W2 halves at the tail)
    if (kt + 3 < NK) {
      x_load(xs0, xs1, n, kt + 2, tid, (kt & 1) ? xrB : xrA);
      w1_gload(Wg, ring + (size_t)((kt + 3) & 3) * 8192, kt + 3, w, lane);
    } else if (kt + 3 == NK) {
      x_load(xs0, xs1, n, kt + 2, tid, (kt & 1) ? xrB : xrA);
      w2_gload_half(W2g, ring + (size_t)(NK & 3) * 8192, 0, w, lane);
    } else if (kt + 3 == NK + 1) {
      w2_gload_half(W2g, ring + (size_t)((NK + 1) & 3) * 8192, 1, w, lane);
    }
    g1_compute(slot, Xl, lrow, lq, Nbase, wm1, acc);
    if (kt + 1 < NK) {
      BAR_LGKM()                  // all waves done reading Xl[kt]
      x_write(Xl, tid, (kt & 1) ? xrA : xrB);   // X[kt+1]; drains W(kt+1) too
      WAIT_BAR12()                // publish + assert (no-op in steady state)
    }
  }
  // caller __syncthreads() drains W2 halves and closes LDS hazards
}

// ---------- GEMM2: C2(256x64) += relu(C1+b1) @ W2 (slots 0,1) ----------
__device__ __forceinline__ void gemm2_branch(f32x4 acc[8][4], f32x4 acc2[2][4],
                                             const float* cA, const float* cB,
                                             const float* __restrict__ b1g,
                                             _Float16* slab, int lrow, int lq,
                                             int Nbase, int wm1, int wn1, int w) {
  int lk8 = lq * 8;
  float bv[4];
#pragma unroll
  for (int nf = 0; nf < 4; ++nf) bv[nf] = b1g[Nbase + nf * 16 + lrow];
#pragma unroll 1
  for (int s = 0; s < 4; ++s) {
    if (wn1 == s) {                       // 2 waves own this 64-col slab of C1
#pragma unroll
      for (int m = 0; m < 8; ++m)
#pragma unroll
        for (int nf = 0; nf < 4; ++nf) {
          f16x4 hv;
#pragma unroll
          for (int r = 0; r < 4; ++r)
            hv[r] = (_Float16)fmaxf(acc[m][nf][r] + bv[nf], 0.f);
          *(f16x4*)(slab + (nf * 16 + lrow) * SLS + wm1 * 128 + m * 16 + lq * 4) = hv;
        }
    }
    __syncthreads();
#pragma unroll
    for (int kf = 0; kf < 2; ++kf) {
      const int r0 = s * 64 + kf * 32;
      const float* wb2 = ((r0 < 128) ? cA : cB) + ((r0 & 127) + lk8) * FD;
      f16x8 a2[2], bb[4];
#pragma unroll
      for (int mf = 0; mf < 2; ++mf) {
        f16x8 t;
#pragma unroll
        for (int j = 0; j < 8; ++j)
          t[j] = slab[(kf * 32 + lk8 + j) * SLS + w * 32 + mf * 16 + lrow];
        a2[mf] = t;
      }
#pragma unroll
      for (int nf = 0; nf < 4; ++nf) {
        int col = (nf * 16 + lrow) ^ (lq << 4);
        f16x8 t;
#pragma unroll
        for (int j = 0; j < 8; ++j) t[j] = (_Float16)wb2[j * FD + col];
        bb[nf] = t;
      }
#pragma unroll
      for (int mf = 0; mf < 2; ++mf)
#pragma unroll
        for (int nf = 0; nf < 4; ++nf)
          acc2[mf][nf] =
              __builtin_amdgcn_mfma_f32_16x16x32_f16(a2[mf], bb[nf], acc2[mf][nf], 0, 0, 0);
    }
    __syncthreads();
  }
}

__global__ __launch_bounds__(512, 2) void phase1_kernel(
    const float* __restrict__ obs, const float* __restrict__ act,
    const float* __restrict__ V_W1, const float* __restrict__ V_b1,
    const float* __restrict__ V_W2, const float* __restrict__ V_b2,
    const float* __restrict__ A_W1, const float* __restrict__ A_b1,
    const float* __restrict__ A_W2, const float* __restrict__ A_b2,
    float* __restrict__ Q) {
  // [0,128KB): W ring (4x32KB; during GEMM2: W2 in slots 0,1, slab in 2,3)
  // [128KB,148KB): X single buffer (256 x XS halves)
  __shared__ __align__(16) float smem[37888];          // 151.5 KB
  float* ring = smem;
  _Float16* Xl = (_Float16*)(smem + 32768);
  _Float16* slab = (_Float16*)(smem + 16384);          // slots 2,3 region

  int tid = threadIdx.x;
  int l = tid & 63, w = tid >> 6, lane = l;
  int lrow = l & 15, lq = l >> 4;
  int wm1 = w >> 2, wn1 = w & 3;      // GEMM1 wave grid 2M x 4N
  int Nbase = wn1 * 64;
  int n = blockIdx.x;                 // 1 node per block per CU

  f32x4 acc[8][4];
  f32x4 acc2[2][4];
#pragma unroll
  for (int i = 0; i < 2; ++i)
#pragma unroll
    for (int j = 0; j < 4; ++j) acc2[i][j] = (f32x4){0.f, 0.f, 0.f, 0.f};

  // ---------------- V branch (NK=8) ----------------
#pragma unroll
  for (int m = 0; m < 8; ++m)
#pragma unroll
    for (int nf = 0; nf < 4; ++nf) acc[m][nf] = (f32x4){0.f, 0.f, 0.f, 0.f};
  run_gemm1<8>(obs, obs, V_W1 + (size_t)n * HD * HD, V_W2 + (size_t)n * HD * FD,
               n, tid, lrow, lq, Nbase, wm1, w, lane, ring, Xl, acc);
  __syncthreads();                    // drains W2 gloads + closes LDS hazards
  gemm2_branch(acc, acc2, ring /*slot0*/, ring + 8192 /*slot1*/,
               V_b1 + n * HD, slab, lrow, lq, Nbase, wm1, wn1, w);

  // ---------------- A branch (NK=16) ----------------
#pragma unroll
  for (int m = 0; m < 8; ++m)
#pragma unroll
    for (int nf = 0; nf < 4; ++nf) acc[m][nf] = (f32x4){0.f, 0.f, 0.f, 0.f};
  run_gemm1<16>(obs, act, A_W1 + (size_t)n * 2 * HD * HD, A_W2 + (size_t)n * HD * FD,
                n, tid, lrow, lq, Nbase, wm1, w, lane, ring, Xl, acc);
  __syncthreads();
  gemm2_branch(acc, acc2, ring /*slot0*/, ring + 8192 /*slot1*/,
               A_b1 + n * HD, slab, lrow, lq, Nbase, wm1, wn1, w);

  // ---------------- Q = acc2 + V_b2 + A_b2 ----------------
  const float* vb2 = V_b2 + n * FD;
  const float* ab2 = A_b2 + n * FD;
#pragma unroll
  for (int mf = 0; mf < 2; ++mf)
#pragma unroll
    for (int nf = 0; nf < 4; ++nf) {
      int f = nf * 16 + lrow;
      float bias = vb2[f] + ab2[f];
#pragma unroll
      for (int rr = 0; rr < 4; ++rr) {
        int row = w * 32 + mf * 16 + lq * 4 + rr;
        Q[(size_t)row * (BN * FD) + n * FD + f] = acc2[mf][nf][rr] + bias;
      }
    }
}

// ---------------- phase 2: gather + subset-min + chi + mean ----------------
__global__ __launch_bounds__(256) void phase2_kernel(const float* __restrict__ Q,
                                                     const float* __restrict__ chi_m,
                                                     const int* __restrict__ le,
                                                     float* __restrict__ out) {
  int b = blockIdx.x;
  int n = threadIdx.x;
  // int64-vs-int32 layout hedge: centers = arange(N) => int32 layout has le[5]==1.
  int step = (le[5] == 1) ? 1 : 2;
  const int* e = le + n * 5 * step;
  int c  = e[0 * step] & (BN - 1);
  int n0 = e[1 * step] & (BN - 1);
  int n1 = e[2 * step] & (BN - 1);
  int n2 = e[3 * step] & (BN - 1);
  int n3 = e[4 * step] & (BN - 1);
  const float* ch = chi_m + n * 45;   // (HEADS=3, S=15)
  float cm[15];
#pragma unroll
  for (int s = 0; s < 15; ++s) cm[s] = (ch[s] + ch[15 + s] + ch[30 + s]) * (1.f / 3.f);
  const float* qb = Q + (size_t)b * (BN * FD);
  const float* q0 = qb + n0 * FD;
  const float* q1 = qb + n1 * FD;
  const float* q2 = qb + n2 * FD;
  const float* q3 = qb + n3 * FD;
  const float* qc = qb + c * FD;
  float acc = 0.f;
#pragma unroll
  for (int f = 0; f < FD; f += 4) {
    float4 v0 = *(const float4*)(q0 + f);
    float4 v1 = *(const float4*)(q1 + f);
    float4 v2 = *(const float4*)(q2 + f);
    float4 v3 = *(const float4*)(q3 + f);
    float4 vc = *(const float4*)(qc + f);
    const float* p0 = (const float*)&v0;
    const float* p1 = (const float*)&v1;
    const float* p2 = (const float*)&v2;
    const float* p3 = (const float*)&v3;
    const float* pc = (const float*)&vc;
#pragma unroll
    for (int u = 0; u < 4; ++u) {
      float a = p0[u], bq = p1[u], cq = p2[u], d = p3[u];
      float m01 = fminf(a, bq), m02 = fminf(a, cq), m03 = fminf(a, d);
      float m12 = fminf(bq, cq), m13 = fminf(bq, d), m23 = fminf(cq, d);
      float m012 = fminf(m01, cq), m013 = fminf(m01, d);
      float m023 = fminf(m02, d),  m123 = fminf(m12, d);
      float m0123 = fminf(m01, m23);
      float chi = cm[0] * a   + cm[1] * bq   + cm[2] * m01  + cm[3] * cq
                + cm[4] * m02 + cm[5] * m12  + cm[6] * m012 + cm[7] * d
                + cm[8] * m03 + cm[9] * m13  + cm[10] * m013 + cm[11] * m23
                + cm[12] * m023 + cm[13] * m123 + cm[14] * m0123;
      acc += chi + pc[u];
    }
  }
  out[b * BN + n] = acc * (1.f / 64.f);
}

extern "C" void kernel_launch(void* const* d_in, const int* in_sizes, int n_in,
                              void* d_out, int out_size, void* d_ws, size_t ws_size,
                              hipStream_t stream) {
  (void)in_sizes; (void)n_in; (void)out_size; (void)ws_size;
  const float* obs  = (const float*)d_in[0];
  const float* act  = (const float*)d_in[1];
  const float* V_W1 = (const float*)d_in[2];
  const float* V_b1 = (const float*)d_in[3];
  const float* V_W2 = (const float*)d_in[4];
  const float* V_b2 = (const float*)d_in[5];
  const float* A_W1 = (const float*)d_in[6];
  const float* A_b1 = (const float*)d_in[7];
  const float* A_W2 = (const float*)d_in[8];
  const float* A_b2 = (const float*)d_in[9];
  const float* chim = (const float*)d_in[10];
  const int*   le   = (const int*)d_in[11];
  float* Q   = (float*)d_ws;            // 16 MB scratch: Q[B][N][F]
  float* out = (float*)d_out;

  phase1_kernel<<<dim3(256), dim3(512), 0, stream>>>(obs, act, V_W1, V_b1, V_W2, V_b2,
                                                     A_W1, A_b1, A_W2, A_b2, Q);
  phase2_kernel<<<dim3(256), dim3(256), 0, stream>>>(Q, chim, le, out);
}

// Round 11
// 143.510 us; speedup vs baseline: 1.1782x; 1.1782x over previous
//
#include <hip/hip_runtime.h>
#include <cstddef>

// Critic_43104291783486 — round 11: two INDEPENDENT blocks per CU.
// grid 512: node = bid&255, batch-half = bid>>8 (pair on same XCD -> L2 dedupe).
// 256 thr / 4 waves, BM=128, acc[8][4]/wave. Ring-2 W via global_load_lds,
// X depth-2 named even/odd batches (no runtime-selected register arrays!),
// GEMM2 = 8 fully-unrolled slab bounces, W2 gloaded into freed ring slots.
// LDS 75KB/block -> exactly 2 blocks/CU; blocks' barriers are uncoupled.

#define BN 256
#define HD 256
#define FD 64
#define XS 40     // X lds row stride (halves)
#define SLS2 132  // slab row stride (halves): 128 rows + 4 pad

typedef _Float16 f16x8 __attribute__((ext_vector_type(8)));
typedef _Float16 f16x4 __attribute__((ext_vector_type(4)));
typedef float f32x4 __attribute__((ext_vector_type(4)));

#define GLOAD16(g, l)                                              \
  __builtin_amdgcn_global_load_lds(                                \
      (__attribute__((address_space(1))) void*)(g),                \
      (__attribute__((address_space(3))) void*)(l), 16, 0, 0)

#define WAIT_BAR(N)                                                        \
  asm volatile("s_waitcnt vmcnt(" #N ") lgkmcnt(0)" ::: "memory");         \
  __builtin_amdgcn_s_barrier();                                            \
  asm volatile("" ::: "memory");
#define BAR_LGKM()                                                         \
  asm volatile("s_waitcnt lgkmcnt(0)" ::: "memory");                       \
  __builtin_amdgcn_s_barrier();                                            \
  asm volatile("" ::: "memory");

// ---------- X staging: 128 rows x 32 k fp32 -> regs -> fp16 LDS ----------
__device__ __forceinline__ void x_load(const float* xs0, const float* xs1, int n,
                                       int row0, int kt, int tid, float4 xr[4]) {
  int kOff = kt * 32;
  const float* xs = (kOff < 256) ? xs0 : xs1;   // A-branch: obs then act
  int row = row0 + (tid >> 1);
  const float* p = xs + (size_t)row * (BN * HD) + n * HD + (kOff & 255) + (tid & 1) * 16;
#pragma unroll
  for (int i = 0; i < 4; ++i) xr[i] = *(const float4*)(p + i * 4);
}
__device__ __forceinline__ void x_write(_Float16* Xl, int tid, const float4 xr[4]) {
  int row = tid >> 1, ko = (tid & 1) * 16;
  const float* f = (const float*)xr;
#pragma unroll
  for (int i = 0; i < 4; ++i) {
    f16x4 v;
    v[0] = (_Float16)f[i * 4 + 0]; v[1] = (_Float16)f[i * 4 + 1];
    v[2] = (_Float16)f[i * 4 + 2]; v[3] = (_Float16)f[i * 4 + 3];
    *(f16x4*)(Xl + row * XS + ko + i * 4) = v;
  }
}

// ---------- W1 tile gload: [32][256] fp32, source pre-swizzled ----------
__device__ __forceinline__ void w1_gload(const float* __restrict__ Wg, float* Wl,
                                         int ktile, int w, int lane) {
#pragma unroll
  for (int s = 0; s < 8; ++s) {
    int rl = w * 8 + s;                    // local row 0..31; rl>>3 == w
    int swz = (w & 3) << 4;
    const float* src = Wg + (size_t)(ktile * 32 + rl) * HD + ((lane * 4) ^ swz);
    GLOAD16(src, Wl + rl * HD);
  }
}

// ---------- W2 half gload: rows half*128..+127 -> chunk[128][64] fp32 ----------
__device__ __forceinline__ void w2_gload_half(const float* __restrict__ W2g, float* chunk,
                                              int half, int w, int lane) {
#pragma unroll
  for (int s = 0; s < 8; ++s) {
    int r0 = (w * 8 + s) * 4;              // 4 rows per gload instr
    int swz = ((r0 >> 3) & 3) << 4;
    const float* src = W2g + (size_t)(half * 128 + r0 + (lane >> 4)) * FD
                       + (((lane & 15) * 4) ^ swz);
    GLOAD16(src, chunk + r0 * FD);
  }
}

// ---------- GEMM1 compute: one 32-k step, 32 MFMA/wave ----------
// A-frag: row = m*16+(l&15), k = lq*8+j.  B-frag: swizzled scalar f32 + cvt.
__device__ __forceinline__ void g1_compute(const float* Wc, const _Float16* Xc,
                                           int lrow, int lq, int Nbase,
                                           f32x4 acc[8][4]) {
  int lk8 = lq * 8;
  const float* wbase = Wc + lk8 * 256;
  f16x8 b[4];
#pragma unroll
  for (int nf = 0; nf < 4; ++nf) {
    int col = (Nbase + nf * 16 + lrow) ^ (lq << 4);
    f16x8 t;
#pragma unroll
    for (int j = 0; j < 8; ++j) t[j] = (_Float16)wbase[j * 256 + col];
    b[nf] = t;
  }
#pragma unroll
  for (int m = 0; m < 8; ++m) {
    f16x8 a = *(const f16x8*)(Xc + (m * 16 + lrow) * XS + lk8);
#pragma unroll
    for (int nf = 0; nf < 4; ++nf)
      acc[m][nf] = __builtin_amdgcn_mfma_f32_16x16x32_f16(a, b[nf], acc[m][nf], 0, 0, 0);
  }
}

// C(128x256) = X(128xK) @ W1(Kx256), K = NK*32 (NK even >= 4).
// Ring-2; per step: issue W(kt+1)+X(kt+2) -> compute -> BAR_LGKM -> x_write
// -> WAIT vmcnt(4) (drain W(kt+1), keep X(kt+2)). Tails fetch W2 halves.
template <int NK>
__device__ __forceinline__ void run_gemm1(const float* xs0, const float* xs1,
                                          const float* __restrict__ Wg,
                                          const float* __restrict__ W2g,
                                          const float* __restrict__ b1g,
                                          int n, int row0, int tid, int lrow, int lq,
                                          int Nbase, int w, int lane,
                                          float* s0, float* s1, _Float16* Xl,
                                          float* b1_lds, f32x4 acc[8][4]) {
  float4 xrA[4], xrB[4];
  // prologue: b1(1) + W0(8) + X0(4) + X1(4)
  GLOAD16(b1g + lane * 4, b1_lds);
  w1_gload(Wg, s0, 0, w, lane);
  x_load(xs0, xs1, n, row0, 0, tid, xrA);
  x_load(xs0, xs1, n, row0, 1, tid, xrB);
  x_write(Xl, tid, xrA);          // implicit wait drains b1,W0,X0; keeps X1
  WAIT_BAR(4)
#pragma unroll 1
  for (int kt = 0; kt <= NK - 4; kt += 2) {
    // even step kt: compute (s0, X[kt])
    w1_gload(Wg, s1, kt + 1, w, lane);
    x_load(xs0, xs1, n, row0, kt + 2, tid, xrA);
    g1_compute(s0, Xl, lrow, lq, Nbase, acc);
    BAR_LGKM()                    // all waves done reading Xl
    x_write(Xl, tid, xrB);        // X[kt+1]; implicit vmcnt(12)
    WAIT_BAR(4)                   // drain W(kt+1); keep X(kt+2)
    // odd step kt+1: compute (s1, X[kt+1])
    w1_gload(Wg, s0, kt + 2, w, lane);
    x_load(xs0, xs1, n, row0, kt + 3, tid, xrB);
    g1_compute(s1, Xl, lrow, lq, Nbase, acc);
    BAR_LGKM()
    x_write(Xl, tid, xrA);        // X[kt+2]
    WAIT_BAR(4)
  }
  // tail step NK-2 (even): compute (s0, X[NK-2])
  w1_gload(Wg, s1, NK - 1, w, lane);
  g1_compute(s0, Xl, lrow, lq, Nbase, acc);
  BAR_LGKM()
  x_write(Xl, tid, xrB);          // X[NK-1]
  WAIT_BAR(0)                     // drain W(NK-1)
  // tail step NK-1 (odd): compute (s1, X[NK-1]); W2 halves into freed slots
  w2_gload_half(W2g, s0, 0, w, lane);
  g1_compute(s1, Xl, lrow, lq, Nbase, acc);
  BAR_LGKM()                      // all waves done with s1 + Xl
  w2_gload_half(W2g, s1, 1, w, lane);
  WAIT_BAR(8)                     // drain W2-half0; half1 stays in flight
}

// ---------- GEMM2: C2(128x64) += relu(C1+b1) @ W2, 8 x 32-k slab bounces ----------
// Fully unrolled (static acc indices). Bounce s: writer wave s>>1 publishes its
// 32 C1-cols; all waves read a2 (slab) + bb (W2 fp32, swizzled) and do 8 MFMA.
__device__ __forceinline__ void gemm2_branch(const f32x4 acc[8][4], f32x4 acc2[2][4],
                                             const float* s0lds, const float* s1lds,
                                             const float* b1_lds, _Float16* slab,
                                             int lrow, int lq, int Nbase, int w) {
  int lk8 = lq * 8;
#pragma unroll
  for (int s = 0; s < 8; ++s) {
    const int wr = s >> 1, nfb = (s & 1) * 2;
    if (w == wr) {
#pragma unroll
      for (int m = 0; m < 8; ++m)
#pragma unroll
        for (int nf2 = 0; nf2 < 2; ++nf2) {
          const int nf = nfb + nf2;                       // static
          float bvv = b1_lds[Nbase + nf * 16 + lrow];
          f16x4 hv;
#pragma unroll
          for (int r = 0; r < 4; ++r)
            hv[r] = (_Float16)fmaxf(acc[m][nf][r] + bvv, 0.f);
          *(f16x4*)(slab + (nf2 * 16 + lrow) * SLS2 + m * 16 + lq * 4) = hv;
        }
    }
    BAR_LGKM()                    // slab published
    const float* chunk = (s < 4) ? s0lds : s1lds;
    const float* wb2 = chunk + ((s & 3) * 32 + lk8) * FD;
    f16x8 a2[2], bb[4];
#pragma unroll
    for (int mf = 0; mf < 2; ++mf) {
      f16x8 t;
#pragma unroll
      for (int j = 0; j < 8; ++j)
        t[j] = slab[(lk8 + j) * SLS2 + w * 32 + mf * 16 + lrow];
      a2[mf] = t;
    }
#pragma unroll
    for (int nf = 0; nf < 4; ++nf) {
      int col = (nf * 16 + lrow) ^ (lq << 4);
      f16x8 t;
#pragma unroll
      for (int j = 0; j < 8; ++j) t[j] = (_Float16)wb2[j * FD + col];
      bb[nf] = t;
    }
#pragma unroll
    for (int mf = 0; mf < 2; ++mf)
#pragma unroll
      for (int nf = 0; nf < 4; ++nf)
        acc2[mf][nf] =
            __builtin_amdgcn_mfma_f32_16x16x32_f16(a2[mf], bb[nf], acc2[mf][nf], 0, 0, 0);
    if (s == 3) { WAIT_BAR(0) }   // W2-half1 must be resident before s=4
    else        { BAR_LGKM() }    // slab reads done before next writer
  }
}

__global__ __launch_bounds__(256, 2) void phase1_kernel(
    const float* __restrict__ obs, const float* __restrict__ act,
    const float* __restrict__ V_W1, const float* __restrict__ V_b1,
    const float* __restrict__ V_W2, const float* __restrict__ V_b2,
    const float* __restrict__ A_W1, const float* __restrict__ A_b1,
    const float* __restrict__ A_W2, const float* __restrict__ A_b2,
    float* __restrict__ Q) {
  // [0,64KB): W ring (2x32KB). [64KB,74KB): X (GEMM1) / slab (GEMM2). [74KB,75KB): b1.
  __shared__ __align__(16) float smem[19200];           // 75 KB -> 2 blocks/CU
  float* s0 = smem;
  float* s1 = smem + 8192;
  _Float16* Xl  = (_Float16*)(smem + 16384);
  _Float16* slab = (_Float16*)(smem + 16384);
  float* b1_lds = smem + 16384 + 2560;

  int tid = threadIdx.x;
  int l = tid & 63, w = tid >> 6, lane = l;
  int lrow = l & 15, lq = l >> 4;
  int Nbase = w * 64;                  // GEMM1: wave owns 64 C1-cols
  int bid = blockIdx.x;
  int n = bid & 255;                   // node
  int row0 = (bid >> 8) * 128;         // batch half; pair (i,i+256) same XCD

  f32x4 acc[8][4];
  f32x4 acc2[2][4];
#pragma unroll
  for (int i = 0; i < 2; ++i)
#pragma unroll
    for (int j = 0; j < 4; ++j) acc2[i][j] = (f32x4){0.f, 0.f, 0.f, 0.f};

  // ---------------- V branch (NK=8) ----------------
#pragma unroll
  for (int m = 0; m < 8; ++m)
#pragma unroll
    for (int nf = 0; nf < 4; ++nf) acc[m][nf] = (f32x4){0.f, 0.f, 0.f, 0.f};
  run_gemm1<8>(obs, obs, V_W1 + (size_t)n * HD * HD, V_W2 + (size_t)n * HD * FD,
               V_b1 + n * HD, n, row0, tid, lrow, lq, Nbase, w, lane,
               s0, s1, Xl, b1_lds, acc);
  gemm2_branch(acc, acc2, s0, s1, b1_lds, slab, lrow, lq, Nbase, w);

  // ---------------- A branch (NK=16) ----------------
#pragma unroll
  for (int m = 0; m < 8; ++m)
#pragma unroll
    for (int nf = 0; nf < 4; ++nf) acc[m][nf] = (f32x4){0.f, 0.f, 0.f, 0.f};
  run_gemm1<16>(obs, act, A_W1 + (size_t)n * 2 * HD * HD, A_W2 + (size_t)n * HD * FD,
                A_b1 + n * HD, n, row0, tid, lrow, lq, Nbase, w, lane,
                s0, s1, Xl, b1_lds, acc);
  gemm2_branch(acc, acc2, s0, s1, b1_lds, slab, lrow, lq, Nbase, w);

  // ---------------- Q = acc2 + V_b2 + A_b2 ----------------
  const float* vb2 = V_b2 + n * FD;
  const float* ab2 = A_b2 + n * FD;
#pragma unroll
  for (int mf = 0; mf < 2; ++mf)
#pragma unroll
    for (int nf = 0; nf < 4; ++nf) {
      int f = nf * 16 + lrow;
      float bias = vb2[f] + ab2[f];
#pragma unroll
      for (int rr = 0; rr < 4; ++rr) {
        int b = row0 + w * 32 + mf * 16 + lq * 4 + rr;
        Q[(size_t)b * (BN * FD) + n * FD + f] = acc2[mf][nf][rr] + bias;
      }
    }
}

// ---------------- phase 2: gather + subset-min + chi + mean ----------------
__global__ __launch_bounds__(256) void phase2_kernel(const float* __restrict__ Q,
                                                     const float* __restrict__ chi_m,
                                                     const int* __restrict__ le,
                                                     float* __restrict__ out) {
  int b = blockIdx.x;
  int n = threadIdx.x;
  // int64-vs-int32 layout hedge: centers = arange(N) => int32 layout has le[5]==1.
  int step = (le[5] == 1) ? 1 : 2;
  const int* e = le + n * 5 * step;
  int c  = e[0 * step] & (BN - 1);
  int n0 = e[1 * step] & (BN - 1);
  int n1 = e[2 * step] & (BN - 1);
  int n2 = e[3 * step] & (BN - 1);
  int n3 = e[4 * step] & (BN - 1);
  const float* ch = chi_m + n * 45;   // (HEADS=3, S=15)
  float cm[15];
#pragma unroll
  for (int s = 0; s < 15; ++s) cm[s] = (ch[s] + ch[15 + s] + ch[30 + s]) * (1.f / 3.f);
  const float* qb = Q + (size_t)b * (BN * FD);
  const float* q0 = qb + n0 * FD;
  const float* q1 = qb + n1 * FD;
  const float* q2 = qb + n2 * FD;
  const float* q3 = qb + n3 * FD;
  const float* qc = qb + c * FD;
  float acc = 0.f;
#pragma unroll
  for (int f = 0; f < FD; f += 4) {
    float4 v0 = *(const float4*)(q0 + f);
    float4 v1 = *(const float4*)(q1 + f);
    float4 v2 = *(const float4*)(q2 + f);
    float4 v3 = *(const float4*)(q3 + f);
    float4 vc = *(const float4*)(qc + f);
    const float* p0 = (const float*)&v0;
    const float* p1 = (const float*)&v1;
    const float* p2 = (const float*)&v2;
    const float* p3 = (const float*)&v3;
    const float* pc = (const float*)&vc;
#pragma unroll
    for (int u = 0; u < 4; ++u) {
      float a = p0[u], bq = p1[u], cq = p2[u], d = p3[u];
      float m01 = fminf(a, bq), m02 = fminf(a, cq), m03 = fminf(a, d);
      float m12 = fminf(bq, cq), m13 = fminf(bq, d), m23 = fminf(cq, d);
      float m012 = fminf(m01, cq), m013 = fminf(m01, d);
      float m023 = fminf(m02, d),  m123 = fminf(m12, d);
      float m0123 = fminf(m01, m23);
      float chi = cm[0] * a   + cm[1] * bq   + cm[2] * m01  + cm[3] * cq
                + cm[4] * m02 + cm[5] * m12  + cm[6] * m012 + cm[7] * d
                + cm[8] * m03 + cm[9] * m13  + cm[10] * m013 + cm[11] * m23
                + cm[12] * m023 + cm[13] * m123 + cm[14] * m0123;
      acc += chi + pc[u];
    }
  }
  out[b * BN + n] = acc * (1.f / 64.f);
}

extern "C" void kernel_launch(void* const* d_in, const int* in_sizes, int n_in,
                              void* d_out, int out_size, void* d_ws, size_t ws_size,
                              hipStream_t stream) {
  (void)in_sizes; (void)n_in; (void)out_size; (void)ws_size;
  const float* obs  = (const float*)d_in[0];
  const float* act  = (const float*)d_in[1];
  const float* V_W1 = (const float*)d_in[2];
  const float* V_b1 = (const float*)d_in[3];
  const float* V_W2 = (const float*)d_in[4];
  const float* V_b2 = (const float*)d_in[5];
  const float* A_W1 = (const float*)d_in[6];
  const float* A_b1 = (const float*)d_in[7];
  const float* A_W2 = (const float*)d_in[8];
  const float* A_b2 = (const float*)d_in[9];
  const float* chim = (const float*)d_in[10];
  const int*   le   = (const int*)d_in[11];
  float* Q   = (float*)d_ws;            // 16 MB scratch: Q[B][N][F]
  float* out = (float*)d_out;

  phase1_kernel<<<dim3(512), dim3(256), 0, stream>>>(obs, act, V_W1, V_b1, V_W2, V_b2,
                                                     A_W1, A_b1, A_W2, A_b2, Q);
  phase2_kernel<<<dim3(256), dim3(256), 0, stream>>>(Q, chim, le, out);
}

// Round 12
// 118.762 us; speedup vs baseline: 1.4237x; 1.2084x over previous
//
#include <hip/hip_runtime.h>
#include <cstddef>

// Critic_43104291783486 — round 12: TLP + all-b128 fragments.
// 21KB LDS / 256-thr block + launch_bounds(256,4) -> 4 blocks/CU = 16 waves/CU
// (4/SIMD; 2x every prior round). All LDS tiles fp16 in [khi][col][klo=8]
// layout so A- and B-frags are single ds_read_b128 (r3-verified mapping).
// Weights reg-round-trip staged per tile (chunked, 8-reg transient); no
// vmcnt(0) drains in the hot loop (lgkm-only raw barriers); per-block staging
// latency is covered by the other 3 resident blocks (TLP bet).
// grid 1024: node = bid&255 (same node -> same XCD -> W L2 dedupe), quarter = bid>>8.

#define BN 256
#define HD 256
#define FD 64
#define NHD (BN * HD)
#define XS 40    // X/slab row stride (halves): 80B rows, b128-aligned at lq*8

typedef _Float16 f16x8 __attribute__((ext_vector_type(8)));
typedef _Float16 f16x4 __attribute__((ext_vector_type(4)));
typedef float f32x4 __attribute__((ext_vector_type(4)));

#define BAR_LGKM()                                                         \
  asm volatile("s_waitcnt lgkmcnt(0)" ::: "memory");                       \
  __builtin_amdgcn_s_barrier();                                            \
  asm volatile("" ::: "memory");

// ---------- X staging: 64 rows x 32 k fp32 -> regs -> fp16 LDS ----------
__device__ __forceinline__ void x_load(const float* xs0, const float* xs1, int n,
                                       int row0, int kt, int tid, float4 xr[2]) {
  int kOff = kt * 32;
  const float* xs = (kOff < 256) ? xs0 : xs1;   // A-branch: obs then act
  int row = tid >> 2, c = (tid & 3) * 4;
  const float* p = xs + (size_t)(row0 + row) * NHD + n * HD + (kOff & 255) + c;
  xr[0] = *(const float4*)p;          // lanes 0-3 cover 64B contiguous
  xr[1] = *(const float4*)(p + 16);
}
__device__ __forceinline__ void x_write(_Float16* Xl, int tid, const float4 xr[2]) {
  int row = tid >> 2, c = (tid & 3) * 4;
  f16x4 a, b;
  a[0] = (_Float16)xr[0].x; a[1] = (_Float16)xr[0].y;
  a[2] = (_Float16)xr[0].z; a[3] = (_Float16)xr[0].w;
  b[0] = (_Float16)xr[1].x; b[1] = (_Float16)xr[1].y;
  b[2] = (_Float16)xr[1].z; b[3] = (_Float16)xr[1].w;
  *(f16x4*)(Xl + row * XS + c) = a;
  *(f16x4*)(Xl + row * XS + c + 16) = b;
}

// ---------- W1 tile stage: 32k x 256 fp32 -> Wl [khi=4][256 col][klo=8] fp16 ----
// Wave w stages k-rows w*8..w*8+7 (khi = w = reader's lq). Per cg chunk:
// 8 coalesced 256B row reads + cvt + one b128 LDS write (8-reg transient).
__device__ __forceinline__ void w1_stage(const float* __restrict__ Wg, _Float16* Wl,
                                         int kt, int w, int l) {
#pragma unroll
  for (int cg = 0; cg < 4; ++cg) {
    int col = cg * 64 + l;
    const float* p = Wg + (size_t)(kt * 32 + w * 8) * HD + col;
    f16x8 v;
#pragma unroll
    for (int r = 0; r < 8; ++r) v[r] = (_Float16)p[(size_t)r * HD];
    *(f16x8*)(Wl + ((size_t)(w * 256 + col)) * 8) = v;
  }
}

// ---------- W2 half stage: rows half*128..+127 -> Wl [khi=16][64 col][klo=8] ----
__device__ __forceinline__ void w2_stage(const float* __restrict__ W2g, _Float16* Wl,
                                         int half, int w, int l) {
#pragma unroll
  for (int cg = 0; cg < 4; ++cg) {
    int khi = w * 4 + cg;
    const float* p = W2g + (size_t)(half * 128 + khi * 8) * FD + l;
    f16x8 v;
#pragma unroll
    for (int r = 0; r < 8; ++r) v[r] = (_Float16)p[(size_t)r * FD];
    *(f16x8*)(Wl + ((size_t)(khi * 64 + l)) * 8) = v;
  }
}

// ---------- GEMM1 compute: one 32-k step, 16 MFMA/wave, all-b128 frags ----------
// A-frag: row = m*16+(l&15), k = lq*8+j (verified r3-r11).
// B-frag: col = Nbase+nf*16+(l&15), k = lq*8+j via [khi=lq][col][klo] (r3-verified).
__device__ __forceinline__ void g1_compute(const _Float16* Wl, const _Float16* Xl,
                                           int lrow, int lq, int Nbase,
                                           f32x4 acc[4][4]) {
  f16x8 b[4];
#pragma unroll
  for (int nf = 0; nf < 4; ++nf)
    b[nf] = *(const f16x8*)(Wl + ((size_t)(lq * 256 + Nbase + nf * 16 + lrow)) * 8);
#pragma unroll
  for (int m = 0; m < 4; ++m) {
    f16x8 a = *(const f16x8*)(Xl + (m * 16 + lrow) * XS + lq * 8);
#pragma unroll
    for (int nf = 0; nf < 4; ++nf)
      acc[m][nf] = __builtin_amdgcn_mfma_f32_16x16x32_f16(a, b[nf], acc[m][nf], 0, 0, 0);
  }
}

// C1(64x256) = X(64xK) @ W1(Kx256), K = NK*32.
template <int NK>
__device__ __forceinline__ void run_gemm1(const float* xs0, const float* xs1,
                                          const float* __restrict__ Wg,
                                          int n, int row0, int tid, int lrow, int lq,
                                          int Nbase, int w, int l,
                                          _Float16* Wl, _Float16* Xl,
                                          f32x4 acc[4][4]) {
  float4 xr[2];
  x_load(xs0, xs1, n, row0, 0, tid, xr);
  w1_stage(Wg, Wl, 0, w, l);
  x_write(Xl, tid, xr);
#pragma unroll 1
  for (int kt = 0; kt < NK; ++kt) {
    BAR_LGKM();                              // tile kt published (LDS writes only)
    if (kt + 1 < NK) x_load(xs0, xs1, n, row0, kt + 1, tid, xr);  // overlaps compute
    g1_compute(Wl, Xl, lrow, lq, Nbase, acc);
    BAR_LGKM();                              // all reads of tile kt done
    if (kt + 1 < NK) {
      w1_stage(Wg, Wl, kt + 1, w, l);        // just-in-time; TLP covers latency
      x_write(Xl, tid, xr);
    }
  }
}

// ---------- GEMM2: C2(64x64) += relu(C1+b1) @ W2, 8 x 32-k slab bounces ----------
// Bounce s: writer wave s>>1 publishes C1 cols s*32..+31 as h into slab[row][klocal];
// all waves: a2 = b128 slab read, bb = b128 W2 reads, 4 MFMA into acc2[4].
__device__ __forceinline__ void gemm2_branch(const f32x4 acc[4][4], f32x4 acc2[4],
                                             const float* __restrict__ W2g,
                                             const float* __restrict__ b1g,
                                             _Float16* Wl, _Float16* slab,
                                             int lrow, int lq, int Nbase, int w, int l) {
  float bv[4];
#pragma unroll
  for (int nf = 0; nf < 4; ++nf) bv[nf] = b1g[Nbase + nf * 16 + lrow];  // L2-hot
  w2_stage(W2g, Wl, 0, w, l);                // W1 reads done (caller's last barrier)
#pragma unroll
  for (int s = 0; s < 8; ++s) {
    if (w == (s >> 1)) {
#pragma unroll
      for (int m = 0; m < 4; ++m)
#pragma unroll
        for (int nf2 = 0; nf2 < 2; ++nf2) {
          const int nf = (s & 1) * 2 + nf2;  // static
#pragma unroll
          for (int r = 0; r < 4; ++r)
            slab[(m * 16 + lq * 4 + r) * XS + nf2 * 16 + lrow] =
                (_Float16)fmaxf(acc[m][nf][r] + bv[nf], 0.f);
        }
    }
    BAR_LGKM();                              // slab (+W2-half writes) published
    f16x8 a2 = *(const f16x8*)(slab + (w * 16 + lrow) * XS + lq * 8);
    f16x8 bb[4];
#pragma unroll
    for (int nf = 0; nf < 4; ++nf)
      bb[nf] = *(const f16x8*)(Wl + ((size_t)(((s & 3) * 4 + lq) * 64 + nf * 16 + lrow)) * 8);
#pragma unroll
    for (int nf = 0; nf < 4; ++nf)
      acc2[nf] = __builtin_amdgcn_mfma_f32_16x16x32_f16(a2, bb[nf], acc2[nf], 0, 0, 0);
    BAR_LGKM();                              // reads done before next writer/stage
    if (s == 3) w2_stage(W2g, Wl, 1, w, l);  // half1 overwrites half0 (reads done)
  }
}

__global__ __launch_bounds__(256, 4) void phase1_kernel(
    const float* __restrict__ obs, const float* __restrict__ act,
    const float* __restrict__ V_W1, const float* __restrict__ V_b1,
    const float* __restrict__ V_W2, const float* __restrict__ V_b2,
    const float* __restrict__ A_W1, const float* __restrict__ A_b1,
    const float* __restrict__ A_W2, const float* __restrict__ A_b2,
    float* __restrict__ Q) {
  // Wl: 8192 halves (16KB) = W1 tile [4][256][8] OR W2 half [16][64][8]
  // Xl: 2560 halves (5KB) = X tile [64][40] (GEMM1) / h slab (GEMM2)
  __shared__ __align__(16) _Float16 Wl[8192];
  __shared__ __align__(16) _Float16 Xl[2560];   // 21KB total -> 4 blocks/CU

  int tid = threadIdx.x;
  int l = tid & 63, w = tid >> 6;
  int lrow = l & 15, lq = l >> 4;
  int Nbase = w * 64;                  // GEMM1: wave owns 64 C1-cols
  int bid = blockIdx.x;
  int n = bid & 255;                   // node; 4 quarters of a node share an XCD
  int row0 = (bid >> 8) * 64;          // batch quarter

  f32x4 acc[4][4];
  f32x4 acc2[4];
#pragma unroll
  for (int j = 0; j < 4; ++j) acc2[j] = (f32x4){0.f, 0.f, 0.f, 0.f};

  // ---------------- V branch (NK=8) ----------------
#pragma unroll
  for (int m = 0; m < 4; ++m)
#pragma unroll
    for (int nf = 0; nf < 4; ++nf) acc[m][nf] = (f32x4){0.f, 0.f, 0.f, 0.f};
  run_gemm1<8>(obs, obs, V_W1 + (size_t)n * HD * HD, n, row0, tid, lrow, lq,
               Nbase, w, l, Wl, Xl, acc);
  gemm2_branch(acc, acc2, V_W2 + (size_t)n * HD * FD, V_b1 + n * HD,
               Wl, Xl, lrow, lq, Nbase, w, l);

  // ---------------- A branch (NK=16) ----------------
#pragma unroll
  for (int m = 0; m < 4; ++m)
#pragma unroll
    for (int nf = 0; nf < 4; ++nf) acc[m][nf] = (f32x4){0.f, 0.f, 0.f, 0.f};
  run_gemm1<16>(obs, act, A_W1 + (size_t)n * 2 * HD * HD, n, row0, tid, lrow, lq,
                Nbase, w, l, Wl, Xl, acc);
  gemm2_branch(acc, acc2, A_W2 + (size_t)n * HD * FD, A_b1 + n * HD,
               Wl, Xl, lrow, lq, Nbase, w, l);

  // ---------------- Q = acc2 + V_b2 + A_b2 ----------------
  const float* vb2 = V_b2 + n * FD;
  const float* ab2 = A_b2 + n * FD;
#pragma unroll
  for (int nf = 0; nf < 4; ++nf) {
    int f = nf * 16 + lrow;
    float bias = vb2[f] + ab2[f];
#pragma unroll
    for (int rr = 0; rr < 4; ++rr) {
      int row = row0 + w * 16 + lq * 4 + rr;
      Q[(size_t)row * (BN * FD) + n * FD + f] = acc2[nf][rr] + bias;
    }
  }
}

// ---------------- phase 2: gather + subset-min + chi + mean ----------------
__global__ __launch_bounds__(256) void phase2_kernel(const float* __restrict__ Q,
                                                     const float* __restrict__ chi_m,
                                                     const int* __restrict__ le,
                                                     float* __restrict__ out) {
  int b = blockIdx.x;
  int n = threadIdx.x;
  // int64-vs-int32 layout hedge: centers = arange(N) => int32 layout has le[5]==1.
  int step = (le[5] == 1) ? 1 : 2;
  const int* e = le + n * 5 * step;
  int c  = e[0 * step] & (BN - 1);
  int n0 = e[1 * step] & (BN - 1);
  int n1 = e[2 * step] & (BN - 1);
  int n2 = e[3 * step] & (BN - 1);
  int n3 = e[4 * step] & (BN - 1);
  const float* ch = chi_m + n * 45;   // (HEADS=3, S=15)
  float cm[15];
#pragma unroll
  for (int s = 0; s < 15; ++s) cm[s] = (ch[s] + ch[15 + s] + ch[30 + s]) * (1.f / 3.f);
  const float* qb = Q + (size_t)b * (BN * FD);
  const float* q0 = qb + n0 * FD;
  const float* q1 = qb + n1 * FD;
  const float* q2 = qb + n2 * FD;
  const float* q3 = qb + n3 * FD;
  const float* qc = qb + c * FD;
  float acc = 0.f;
#pragma unroll
  for (int f = 0; f < FD; f += 4) {
    float4 v0 = *(const float4*)(q0 + f);
    float4 v1 = *(const float4*)(q1 + f);
    float4 v2 = *(const float4*)(q2 + f);
    float4 v3 = *(const float4*)(q3 + f);
    float4 vc = *(const float4*)(qc + f);
    const float* p0 = (const float*)&v0;
    const float* p1 = (const float*)&v1;
    const float* p2 = (const float*)&v2;
    const float* p3 = (const float*)&v3;
    const float* pc = (const float*)&vc;
#pragma unroll
    for (int u = 0; u < 4; ++u) {
      float a = p0[u], bq = p1[u], cq = p2[u], d = p3[u];
      float m01 = fminf(a, bq), m02 = fminf(a, cq), m03 = fminf(a, d);
      float m12 = fminf(bq, cq), m13 = fminf(bq, d), m23 = fminf(cq, d);
      float m012 = fminf(m01, cq), m013 = fminf(m01, d);
      float m023 = fminf(m02, d),  m123 = fminf(m12, d);
      float m0123 = fminf(m01, m23);
      float chi = cm[0] * a   + cm[1] * bq   + cm[2] * m01  + cm[3] * cq
                + cm[4] * m02 + cm[5] * m12  + cm[6] * m012 + cm[7] * d
                + cm[8] * m03 + cm[9] * m13  + cm[10] * m013 + cm[11] * m23
                + cm[12] * m023 + cm[13] * m123 + cm[14] * m0123;
      acc += chi + pc[u];
    }
  }
  out[b * BN + n] = acc * (1.f / 64.f);
}

extern "C" void kernel_launch(void* const* d_in, const int* in_sizes, int n_in,
                              void* d_out, int out_size, void* d_ws, size_t ws_size,
                              hipStream_t stream) {
  (void)in_sizes; (void)n_in; (void)out_size; (void)ws_size;
  const float* obs  = (const float*)d_in[0];
  const float* act  = (const float*)d_in[1];
  const float* V_W1 = (const float*)d_in[2];
  const float* V_b1 = (const float*)d_in[3];
  const float* V_W2 = (const float*)d_in[4];
  const float* V_b2 = (const float*)d_in[5];
  const float* A_W1 = (const float*)d_in[6];
  const float* A_b1 = (const float*)d_in[7];
  const float* A_W2 = (const float*)d_in[8];
  const float* A_b2 = (const float*)d_in[9];
  const float* chim = (const float*)d_in[10];
  const int*   le   = (const int*)d_in[11];
  float* Q   = (float*)d_ws;            // 16 MB scratch: Q[B][N][F]
  float* out = (float*)d_out;

  phase1_kernel<<<dim3(1024), dim3(256), 0, stream>>>(obs, act, V_W1, V_b1, V_W2, V_b2,
                                                      A_W1, A_b1, A_W2, A_b2, Q);
  phase2_kernel<<<dim3(256), dim3(256), 0, stream>>>(Q, chim, le, out);
}